// Round 1
// baseline (11329.795 us; speedup 1.0000x reference)
//
#include <hip/hip_runtime.h>
#include <math.h>

#define BB 8
#define TT 512
#define HH 8
#define ESS 96
#define EMBD 768
#define FFD 3072
#define NLAYER 6

// ---------------------------------------------------------------------------
// Generic tiled GEMM: C = alpha * A * B^T + beta * C (+bias[n]) (+exact gelu)
// A: M x K (row pitch lda), B: N x K (row pitch ldb), C: M x N (pitch ldc)
// Batched via blockIdx.z with z -> (zb = z/bdiv, zh = z%bdiv) stride pairs.
// ---------------------------------------------------------------------------
#define BM 64
#define BN 64
#define BK 16

__global__ __launch_bounds__(256) void gemm_abt(
    const float* __restrict__ A, int lda,
    const float* __restrict__ B, int ldb,
    float* __restrict__ C, int ldc,
    int M, int N, int K,
    float alpha, float beta,
    const float* __restrict__ bias, int gelu,
    int bdiv, long sAb, long sAh, long sBb, long sBh, long sCb, long sCh)
{
    const int z = blockIdx.z;
    const int zb = z / bdiv, zh = z % bdiv;
    A += (long)zb * sAb + (long)zh * sAh;
    B += (long)zb * sBb + (long)zh * sBh;
    C += (long)zb * sCb + (long)zh * sCh;

    __shared__ float As[BK][BM + 4];
    __shared__ float Bs[BK][BN + 4];

    const int m0 = blockIdx.y * BM;
    const int n0 = blockIdx.x * BN;
    const int tid = threadIdx.x;
    const int tx = tid & 15, ty = tid >> 4;

    float acc[4][4] = {};

    for (int k0 = 0; k0 < K; k0 += BK) {
#pragma unroll
        for (int c = 0; c < 4; ++c) {
            int li = tid + 256 * c;
            int row = li >> 4, col = li & 15;
            int gm = m0 + row, gk = k0 + col;
            As[col][row] = (gm < M && gk < K) ? A[(long)gm * lda + gk] : 0.f;
        }
#pragma unroll
        for (int c = 0; c < 4; ++c) {
            int li = tid + 256 * c;
            int row = li >> 4, col = li & 15;
            int gn = n0 + row, gk = k0 + col;
            Bs[col][row] = (gn < N && gk < K) ? B[(long)gn * ldb + gk] : 0.f;
        }
        __syncthreads();
#pragma unroll
        for (int kk = 0; kk < BK; ++kk) {
            float4 a4 = *(const float4*)&As[kk][ty * 4];
            float4 b4 = *(const float4*)&Bs[kk][tx * 4];
            float a[4] = {a4.x, a4.y, a4.z, a4.w};
            float b[4] = {b4.x, b4.y, b4.z, b4.w};
#pragma unroll
            for (int i = 0; i < 4; ++i)
#pragma unroll
                for (int j = 0; j < 4; ++j)
                    acc[i][j] = fmaf(a[i], b[j], acc[i][j]);
        }
        __syncthreads();
    }

#pragma unroll
    for (int i = 0; i < 4; ++i) {
        int gm = m0 + ty * 4 + i;
        if (gm >= M) continue;
#pragma unroll
        for (int j = 0; j < 4; ++j) {
            int gn = n0 + tx * 4 + j;
            if (gn >= N) continue;
            float v = alpha * acc[i][j];
            if (beta != 0.f) v = fmaf(beta, C[(long)gm * ldc + gn], v);
            if (bias) v += bias[gn];
            if (gelu) v = 0.5f * v * (1.f + erff(v * 0.70710678118654752f));
            C[(long)gm * ldc + gn] = v;
        }
    }
}

// ---------------------------------------------------------------------------
// Fused softmax (over key axis) + PV for one (b,h), 16 query rows per block.
// prev: (B*H, T, T) raw scores (already includes residual add).
// kqv : (B, T, H, 288) with f = [k(0:96) | q(96:192) | v(192:288)]
// out : (B, T, EMB) attention output (head-merged), fp32
// block = 192 threads (3 waves)
// ---------------------------------------------------------------------------
__global__ __launch_bounds__(192) void softmax_pv(
    const float* __restrict__ prev,
    const float* __restrict__ kqv,
    float* __restrict__ out)
{
    const int z = blockIdx.z;           // b*H + h
    const int b = z / HH, h = z % HH;
    const int i0 = blockIdx.x * 16;
    const float* Sbh = prev + (long)z * TT * TT;

    __shared__ float p[16][TT];         // 32 KiB: softmaxed rows
    __shared__ float VsT[ESS][68];      // ~26 KiB: transposed V chunk (64 keys)

    const int tid = threadIdx.x;
    const int wv = tid / 64, lane = tid & 63;

    // phase 1: row softmax (each wave handles up to 6 rows)
    int r_begin = wv * 6;
    int r_end = (wv * 6 + 6 < 16) ? (wv * 6 + 6) : 16;
    for (int r = r_begin; r < r_end; ++r) {
        const float* Srow = Sbh + (long)(i0 + r) * TT;
        float vals[8];
        float mx = -1e30f;
#pragma unroll
        for (int c = 0; c < 8; ++c) { vals[c] = Srow[lane + 64 * c]; mx = fmaxf(mx, vals[c]); }
        for (int o = 32; o; o >>= 1) mx = fmaxf(mx, __shfl_xor(mx, o));
        float sum = 0.f;
#pragma unroll
        for (int c = 0; c < 8; ++c) { vals[c] = __expf(vals[c] - mx); sum += vals[c]; }
        for (int o = 32; o; o >>= 1) sum += __shfl_xor(sum, o);
        float inv = 1.f / sum;
#pragma unroll
        for (int c = 0; c < 8; ++c) p[r][lane + 64 * c] = vals[c] * inv;
    }
    __syncthreads();

    // phase 2: PV. thread -> (s = tid%96, half = tid/96 owning rows half*8..+7)
    const int s = tid % ESS;
    const int half = tid / ESS;
    float acc[8] = {};

    for (int j0 = 0; j0 < TT; j0 += 64) {
        // stage V[j0..j0+63][0..95] transposed
#pragma unroll
        for (int c = 0; c < 32; ++c) {
            int li = tid + 192 * c;     // 0..6143
            int jr = li / ESS, ss = li % ESS;
            VsT[ss][jr] = kqv[((long)(b * TT + j0 + jr) * HH + h) * 288 + 192 + ss];
        }
        __syncthreads();
#pragma unroll
        for (int jj = 0; jj < 64; jj += 4) {
            float4 v4 = *(const float4*)&VsT[s][jj];
#pragma unroll
            for (int r = 0; r < 8; ++r) {
                float4 p4 = *(const float4*)&p[half * 8 + r][j0 + jj];
                acc[r] += p4.x * v4.x + p4.y * v4.y + p4.z * v4.z + p4.w * v4.w;
            }
        }
        __syncthreads();
    }

#pragma unroll
    for (int r = 0; r < 8; ++r)
        out[(long)(b * TT + i0 + half * 8 + r) * EMBD + h * ESS + s] = acc[r];
}

// ---------------------------------------------------------------------------
// x = LayerNorm(x + res) * g + b   (row = one (b,t), 768 elems, 256 threads)
// ---------------------------------------------------------------------------
__global__ __launch_bounds__(256) void add_ln(
    float* __restrict__ x, const float* __restrict__ res,
    const float* __restrict__ g, const float* __restrict__ bta)
{
    const long row = blockIdx.x;
    float* xr = x + row * EMBD;
    const float* rr = res + row * EMBD;
    __shared__ float sh[8];
    const int tid = threadIdx.x;
    const int lane = tid & 63, w = tid >> 6;

    float v[3];
    float s = 0.f;
#pragma unroll
    for (int c = 0; c < 3; ++c) { int i = tid + 256 * c; v[c] = xr[i] + rr[i]; s += v[c]; }
    for (int o = 32; o; o >>= 1) s += __shfl_xor(s, o);
    if (lane == 0) sh[w] = s;
    __syncthreads();
    float mu = (sh[0] + sh[1] + sh[2] + sh[3]) * (1.f / EMBD);

    float var = 0.f;
#pragma unroll
    for (int c = 0; c < 3; ++c) { float d = v[c] - mu; var += d * d; }
    for (int o = 32; o; o >>= 1) var += __shfl_xor(var, o);
    __syncthreads();
    if (lane == 0) sh[w] = var;
    __syncthreads();
    var = (sh[0] + sh[1] + sh[2] + sh[3]) * (1.f / EMBD);
    float rstd = rsqrtf(var + 1e-5f);
#pragma unroll
    for (int c = 0; c < 3; ++c) {
        int i = tid + 256 * c;
        xr[i] = (v[c] - mu) * rstd * g[i] + bta[i];
    }
}

// ---------------------------------------------------------------------------
extern "C" void kernel_launch(void* const* d_in, const int* in_sizes, int n_in,
                              void* d_out, int out_size, void* d_ws, size_t ws_size,
                              hipStream_t stream) {
    const float* x_in  = (const float*)d_in[0];
    const float* Wkqv  = (const float*)d_in[1];
    const float* Wproj = (const float*)d_in[2];
    const float* ln1_g = (const float*)d_in[3];
    const float* ln1_b = (const float*)d_in[4];
    const float* ln2_g = (const float*)d_in[5];
    const float* ln2_b = (const float*)d_in[6];
    const float* ff_w1 = (const float*)d_in[7];
    const float* ff_b1 = (const float*)d_in[8];
    const float* ff_w2 = (const float*)d_in[9];
    const float* ff_b2 = (const float*)d_in[10];

    float* x = (float*)d_out;                 // running activations (B,T,EMB)
    char* ws = (char*)d_ws;
    float* prev = (float*)(ws);                          // (B*H,T,T)   64 MiB
    float* kqvb = (float*)(ws + 67108864);               // (B,T,H,288) 36 MiB
    float* attn = (float*)(ws + 104857600);              // (B,T,EMB)   12 MiB
    float* res  = (float*)(ws + 117440512);              // (B,T,EMB)   12 MiB
    float* h1   = (float*)(ws + 130023424);              // (B,T,4EMB)  48 MiB

    hipMemcpyAsync(x, x_in, (size_t)BB * TT * EMBD * sizeof(float),
                   hipMemcpyDeviceToDevice, stream);
    hipMemsetAsync(prev, 0, (size_t)BB * HH * TT * TT * sizeof(float), stream);

    const float scale = 0.10206207261596577f;  // 1/sqrt(96)

    for (int l = 0; l < NLAYER; ++l) {
        const float* wkqv = Wkqv + (size_t)l * 3 * ESS * ESS;
        const float* wproj = Wproj + (size_t)l * EMBD * EMBD;
        const float* w1 = ff_w1 + (size_t)l * FFD * EMBD;
        const float* b1 = ff_b1 + (size_t)l * FFD;
        const float* w2 = ff_w2 + (size_t)l * EMBD * FFD;
        const float* b2 = ff_b2 + (size_t)l * EMBD;

        // kqv = x(32768,96) @ wkqv(288,96)^T  -> (B,T,H,288)
        gemm_abt<<<dim3(5, 512, 1), 256, 0, stream>>>(
            x, ESS, wkqv, ESS, kqvb, 288,
            BB * TT * HH, 288, ESS, 1.f, 0.f, nullptr, 0,
            1, 0, 0, 0, 0, 0, 0);

        // prev = Q K^T * scale + prev   (batched over b,h; in-place raw scores)
        gemm_abt<<<dim3(8, 8, BB * HH), 256, 0, stream>>>(
            kqvb + ESS /*q*/, HH * 288, kqvb /*k*/, HH * 288, prev, TT,
            TT, TT, ESS, scale, 1.f, nullptr, 0,
            HH, (long)TT * HH * 288, 288, (long)TT * HH * 288, 288,
            (long)HH * TT * TT, (long)TT * TT);

        // attn = softmax(prev) @ V  (head-merged)
        softmax_pv<<<dim3(TT / 16, 1, BB * HH), 192, 0, stream>>>(prev, kqvb, attn);

        // res = attn @ Wproj^T
        gemm_abt<<<dim3(12, 64, 1), 256, 0, stream>>>(
            attn, EMBD, wproj, EMBD, res, EMBD,
            BB * TT, EMBD, EMBD, 1.f, 0.f, nullptr, 0,
            1, 0, 0, 0, 0, 0, 0);

        // x = LN1(x + res)
        add_ln<<<BB * TT, 256, 0, stream>>>(x, res, ln1_g + (size_t)l * EMBD, ln1_b + (size_t)l * EMBD);

        // h1 = gelu(x @ w1^T + b1)
        gemm_abt<<<dim3(48, 64, 1), 256, 0, stream>>>(
            x, EMBD, w1, EMBD, h1, FFD,
            BB * TT, FFD, EMBD, 1.f, 0.f, b1, 1,
            1, 0, 0, 0, 0, 0, 0);

        // res = h1 @ w2^T + b2
        gemm_abt<<<dim3(12, 64, 1), 256, 0, stream>>>(
            h1, FFD, w2, FFD, res, EMBD,
            BB * TT, EMBD, FFD, 1.f, 0.f, b2, 0,
            1, 0, 0, 0, 0, 0, 0);

        // x = LN2(x + res)
        add_ln<<<BB * TT, 256, 0, stream>>>(x, res, ln2_g + (size_t)l * EMBD, ln2_b + (size_t)l * EMBD);
    }
}

// Round 2
// 1827.959 us; speedup vs baseline: 6.1981x; 6.1981x over previous
//
#include <hip/hip_runtime.h>
#include <math.h>

#define BB 8
#define TT 512
#define HH 8
#define ESS 96
#define EMBD 768
#define FFD 3072
#define NLAYER 6

typedef unsigned short ushort_t;
typedef __attribute__((ext_vector_type(8))) short short8;
typedef __attribute__((ext_vector_type(4))) float f32x4;
typedef __attribute__((ext_vector_type(4))) unsigned short ushort4v;

static __device__ __forceinline__ ushort_t f2b(float f) {
    unsigned u = __builtin_bit_cast(unsigned, f);
    unsigned r = (u + 0x7fffu + ((u >> 16) & 1u)) >> 16;
    return (ushort_t)r;
}

// ---------------------------------------------------------------------------
// fp32 tiled GEMM: C = alpha * A * B^T + beta * C  (kqv + score only)
// ---------------------------------------------------------------------------
#define BMf 64
#define BNf 64
#define BKf 16

__global__ __launch_bounds__(256) void gemm_abt(
    const float* __restrict__ A, int lda,
    const float* __restrict__ B, int ldb,
    float* __restrict__ C, int ldc,
    int M, int N, int K,
    float alpha, float beta,
    int bdiv, long sAb, long sAh, long sBb, long sBh, long sCb, long sCh)
{
    const int z = blockIdx.z;
    const int zb = z / bdiv, zh = z % bdiv;
    A += (long)zb * sAb + (long)zh * sAh;
    B += (long)zb * sBb + (long)zh * sBh;
    C += (long)zb * sCb + (long)zh * sCh;

    __shared__ float As[BKf][BMf + 4];
    __shared__ float Bs[BKf][BNf + 4];

    const int m0 = blockIdx.y * BMf;
    const int n0 = blockIdx.x * BNf;
    const int tid = threadIdx.x;
    const int tx = tid & 15, ty = tid >> 4;

    float acc[4][4] = {};

    for (int k0 = 0; k0 < K; k0 += BKf) {
#pragma unroll
        for (int c = 0; c < 4; ++c) {
            int li = tid + 256 * c;
            int row = li >> 4, col = li & 15;
            int gm = m0 + row, gk = k0 + col;
            As[col][row] = (gm < M && gk < K) ? A[(long)gm * lda + gk] : 0.f;
        }
#pragma unroll
        for (int c = 0; c < 4; ++c) {
            int li = tid + 256 * c;
            int row = li >> 4, col = li & 15;
            int gn = n0 + row, gk = k0 + col;
            Bs[col][row] = (gn < N && gk < K) ? B[(long)gn * ldb + gk] : 0.f;
        }
        __syncthreads();
#pragma unroll
        for (int kk = 0; kk < BKf; ++kk) {
            float4 a4 = *(const float4*)&As[kk][ty * 4];
            float4 b4 = *(const float4*)&Bs[kk][tx * 4];
            float a[4] = {a4.x, a4.y, a4.z, a4.w};
            float b[4] = {b4.x, b4.y, b4.z, b4.w};
#pragma unroll
            for (int i = 0; i < 4; ++i)
#pragma unroll
                for (int j = 0; j < 4; ++j)
                    acc[i][j] = fmaf(a[i], b[j], acc[i][j]);
        }
        __syncthreads();
    }

#pragma unroll
    for (int i = 0; i < 4; ++i) {
        int gm = m0 + ty * 4 + i;
        if (gm >= M) continue;
#pragma unroll
        for (int j = 0; j < 4; ++j) {
            int gn = n0 + tx * 4 + j;
            if (gn >= N) continue;
            float v = alpha * acc[i][j];
            if (beta != 0.f) v = fmaf(beta, C[(long)gm * ldc + gn], v);
            C[(long)gm * ldc + gn] = v;
        }
    }
}

// ---------------------------------------------------------------------------
// bf16 MFMA GEMM: C = A(M,K) * B(N,K)^T (+bias) (+gelu), bf16 or fp32 out.
// BM=128 fixed, BK=32, 256 threads (4 waves, WM x WN wave grid).
// Staging via global_load_lds width 16 (linear LDS, K-major tiles).
// ---------------------------------------------------------------------------
template<int BN, int WM, int WN, int OUTBF, int HASBIAS, int GELU>
__global__ __launch_bounds__(256) void gemm_mfma(
    const ushort_t* __restrict__ A, int lda,
    const ushort_t* __restrict__ B, int ldb,
    void* __restrict__ Cv, int ldc,
    int K,
    const float* __restrict__ bias,
    int bdiv, long sAb, long sAh, long sBb, long sBh, long sCb, long sCh)
{
    constexpr int BM = 128, BK = 32;
    constexpr int WTM = BM / WM;
    constexpr int WTN = BN / WN;
    constexpr int MF = WTM / 16, NF = WTN / 16;
    constexpr int ACH = (BM * BK * 2) / 1024;   // 8 chunks of 1 KiB
    constexpr int BCH = (BN * BK * 2) / 1024;   // 8 / 6 / 4

    const int z = blockIdx.z;
    const int zb = z / bdiv, zh = z % bdiv;
    A += (long)zb * sAb + (long)zh * sAh;
    B += (long)zb * sBb + (long)zh * sBh;
    const long coff = (long)zb * sCb + (long)zh * sCh;

    __shared__ ushort_t As[BM * BK];
    __shared__ ushort_t Bs[BN * BK];

    const int tid = threadIdx.x;
    const int w = tid >> 6, lane = tid & 63;
    const int wr = w / WN, wc = w % WN;
    const int m0 = blockIdx.y * BM;
    const int n0 = blockIdx.x * BN;

    f32x4 acc[MF][NF] = {};

    const int fr = lane & 15;     // fragment row (A) / col (B)
    const int kb = lane >> 4;     // k-block: k = kb*8 .. +7

    for (int k0 = 0; k0 < K; k0 += BK) {
        // ---- stage A tile [128][32] (8 KiB) ----
#pragma unroll
        for (int q = 0; q < 2; ++q) {
            int ci = q * 4 + w;
            if (ci < ACH) {
                int e = ci * 512 + lane * 8;
                int r = e >> 5, c = e & 31;
                const ushort_t* gp = A + (long)(m0 + r) * lda + (k0 + c);
                __builtin_amdgcn_global_load_lds(
                    (const __attribute__((address_space(1))) void*)gp,
                    (__attribute__((address_space(3))) void*)((char*)As + ci * 1024),
                    16, 0, 0);
            }
        }
        // ---- stage B tile [BN][32] ----
#pragma unroll
        for (int q = 0; q < (BCH + 3) / 4; ++q) {
            int ci = q * 4 + w;
            if (ci < BCH) {
                int e = ci * 512 + lane * 8;
                int r = e >> 5, c = e & 31;
                const ushort_t* gp = B + (long)(n0 + r) * ldb + (k0 + c);
                __builtin_amdgcn_global_load_lds(
                    (const __attribute__((address_space(1))) void*)gp,
                    (__attribute__((address_space(3))) void*)((char*)Bs + ci * 1024),
                    16, 0, 0);
            }
        }
        __syncthreads();

        short8 af[MF], bfr[NF];
#pragma unroll
        for (int fm = 0; fm < MF; ++fm)
            af[fm] = *(const short8*)&As[(wr * WTM + fm * 16 + fr) * 32 + kb * 8];
#pragma unroll
        for (int fn = 0; fn < NF; ++fn)
            bfr[fn] = *(const short8*)&Bs[(wc * WTN + fn * 16 + fr) * 32 + kb * 8];
#pragma unroll
        for (int fm = 0; fm < MF; ++fm)
#pragma unroll
            for (int fn = 0; fn < NF; ++fn)
                acc[fm][fn] = __builtin_amdgcn_mfma_f32_16x16x32_bf16(
                    af[fm], bfr[fn], acc[fm][fn], 0, 0, 0);
        __syncthreads();
    }

    // ---- epilogue: C/D layout col = lane&15, row = (lane>>4)*4 + j ----
    const int cr = lane >> 4;
    const int cc = lane & 15;
#pragma unroll
    for (int fm = 0; fm < MF; ++fm) {
#pragma unroll
        for (int fn = 0; fn < NF; ++fn) {
#pragma unroll
            for (int j = 0; j < 4; ++j) {
                int gm = m0 + wr * WTM + fm * 16 + cr * 4 + j;
                int gn = n0 + wc * WTN + fn * 16 + cc;
                float v = acc[fm][fn][j];
                if (HASBIAS) v += bias[gn];
                if (GELU) v = 0.5f * v * (1.f + erff(v * 0.70710678118654752f));
                long idx = coff + (long)gm * ldc + gn;
                if (OUTBF) ((ushort_t*)Cv)[idx] = f2b(v);
                else       ((float*)Cv)[idx] = v;
            }
        }
    }
}

// ---------------------------------------------------------------------------
// Row softmax: one wave per 512-elem score row, bf16 output.
// ---------------------------------------------------------------------------
__global__ __launch_bounds__(256) void softmax_rows(
    const float* __restrict__ S, ushort_t* __restrict__ P)
{
    const long row = (long)blockIdx.x * 4 + (threadIdx.x >> 6);
    const int lane = threadIdx.x & 63;
    const float4* S4 = (const float4*)(S + row * TT);
    float4 a = S4[lane];
    float4 b = S4[lane + 64];
    float v[8] = {a.x, a.y, a.z, a.w, b.x, b.y, b.z, b.w};
    float mx = -1e30f;
#pragma unroll
    for (int i = 0; i < 8; ++i) mx = fmaxf(mx, v[i]);
    for (int o = 32; o; o >>= 1) mx = fmaxf(mx, __shfl_xor(mx, o));
    float sum = 0.f;
#pragma unroll
    for (int i = 0; i < 8; ++i) { v[i] = __expf(v[i] - mx); sum += v[i]; }
    for (int o = 32; o; o >>= 1) sum += __shfl_xor(sum, o);
    float inv = 1.f / sum;
    ushort4v o1 = {f2b(v[0] * inv), f2b(v[1] * inv), f2b(v[2] * inv), f2b(v[3] * inv)};
    ushort4v o2 = {f2b(v[4] * inv), f2b(v[5] * inv), f2b(v[6] * inv), f2b(v[7] * inv)};
    ushort4v* P4 = (ushort4v*)(P + row * TT);
    P4[lane] = o1;
    P4[lane + 64] = o2;
}

// ---------------------------------------------------------------------------
// Extract V from interleaved kqv and write V^T bf16: Vt[(b,h,s),t]
// ---------------------------------------------------------------------------
__global__ __launch_bounds__(256) void vt_cvt(
    const float* __restrict__ kqv, ushort_t* __restrict__ Vt)
{
    const int idx = blockIdx.x * 256 + threadIdx.x;   // B*H*96*512 total
    const int t = idx & 511;
    const int rest = idx >> 9;
    const int s = rest % ESS;
    const int bh = rest / ESS;
    const int h = bh & 7, b = bh >> 3;
    float v = kqv[(((long)(b * TT + t) * HH + h) * 288) + 192 + s];
    Vt[idx] = f2b(v);
}

// ---------------------------------------------------------------------------
// fp32 -> bf16 convert (weights), vectorized x4
// ---------------------------------------------------------------------------
__global__ __launch_bounds__(256) void cvt_f2b(
    const float* __restrict__ in, ushort_t* __restrict__ out)
{
    const int i = blockIdx.x * 256 + threadIdx.x;
    float4 v = ((const float4*)in)[i];
    ushort4v o = {f2b(v.x), f2b(v.y), f2b(v.z), f2b(v.w)};
    ((ushort4v*)out)[i] = o;
}

// ---------------------------------------------------------------------------
// x = LayerNorm(x + res) * g + b ; also emit bf16 copy of x
// ---------------------------------------------------------------------------
__global__ __launch_bounds__(256) void add_ln(
    float* __restrict__ x, const float* __restrict__ res,
    const float* __restrict__ g, const float* __restrict__ bta,
    ushort_t* __restrict__ xb)
{
    const long row = blockIdx.x;
    float* xr = x + row * EMBD;
    ushort_t* xbr = xb + row * EMBD;
    const float* rr = res + row * EMBD;
    __shared__ float sh[8];
    const int tid = threadIdx.x;
    const int lane = tid & 63, w = tid >> 6;

    float v[3];
    float s = 0.f;
#pragma unroll
    for (int c = 0; c < 3; ++c) { int i = tid + 256 * c; v[c] = xr[i] + rr[i]; s += v[c]; }
    for (int o = 32; o; o >>= 1) s += __shfl_xor(s, o);
    if (lane == 0) sh[w] = s;
    __syncthreads();
    float mu = (sh[0] + sh[1] + sh[2] + sh[3]) * (1.f / EMBD);

    float var = 0.f;
#pragma unroll
    for (int c = 0; c < 3; ++c) { float d = v[c] - mu; var += d * d; }
    for (int o = 32; o; o >>= 1) var += __shfl_xor(var, o);
    __syncthreads();
    if (lane == 0) sh[w] = var;
    __syncthreads();
    var = (sh[0] + sh[1] + sh[2] + sh[3]) * (1.f / EMBD);
    float rstd = rsqrtf(var + 1e-5f);
#pragma unroll
    for (int c = 0; c < 3; ++c) {
        int i = tid + 256 * c;
        float o = (v[c] - mu) * rstd * g[i] + bta[i];
        xr[i] = o;
        xbr[i] = f2b(o);
    }
}

// ---------------------------------------------------------------------------
extern "C" void kernel_launch(void* const* d_in, const int* in_sizes, int n_in,
                              void* d_out, int out_size, void* d_ws, size_t ws_size,
                              hipStream_t stream) {
    const float* x_in  = (const float*)d_in[0];
    const float* Wkqv  = (const float*)d_in[1];
    const float* Wproj = (const float*)d_in[2];
    const float* ln1_g = (const float*)d_in[3];
    const float* ln1_b = (const float*)d_in[4];
    const float* ln2_g = (const float*)d_in[5];
    const float* ln2_b = (const float*)d_in[6];
    const float* ff_w1 = (const float*)d_in[7];
    const float* ff_b1 = (const float*)d_in[8];
    const float* ff_w2 = (const float*)d_in[9];
    const float* ff_b2 = (const float*)d_in[10];

    float* x = (float*)d_out;                 // running activations (B,T,EMB) fp32
    char* ws = (char*)d_ws;
    // layout (bytes):
    float*    prev   = (float*)(ws);                      //  0        .. 64MiB   (B*H,T,T) fp32
    float*    kqvb   = (float*)(ws + 67108864);           //  union: kqv fp32 (36MiB)
    ushort_t* Pb     = (ushort_t*)(ws + 67108864);        //  union: P bf16 (32MiB)
    ushort_t* h1b    = (ushort_t*)(ws + 67108864);        //  union: h1 bf16 (24MiB)
    float*    res    = (float*)(ws + 104857600);          //  (B,T,EMB) fp32 12MiB
    ushort_t* xb     = (ushort_t*)(ws + 117440512);       //  (B,T,EMB) bf16 6MiB
    ushort_t* attnb  = (ushort_t*)(ws + 123731968);       //  (B,T,EMB) bf16 6MiB
    ushort_t* Vtb    = (ushort_t*)(ws + 130023424);       //  (B,H,96,T) bf16 6MiB
    ushort_t* Wprojb = (ushort_t*)(ws + 136314880);       //  768*768 bf16
    ushort_t* W1b    = (ushort_t*)(ws + 137494528);       //  3072*768 bf16
    ushort_t* W2b    = (ushort_t*)(ws + 142213120);       //  768*3072 bf16 (end ~140MiB)

    hipMemcpyAsync(x, x_in, (size_t)BB * TT * EMBD * sizeof(float),
                   hipMemcpyDeviceToDevice, stream);
    hipMemsetAsync(prev, 0, (size_t)BB * HH * TT * TT * sizeof(float), stream);

    const float scale = 0.10206207261596577f;  // 1/sqrt(96)

    for (int l = 0; l < NLAYER; ++l) {
        const float* wkqv  = Wkqv + (size_t)l * 3 * ESS * ESS;
        const float* wproj = Wproj + (size_t)l * EMBD * EMBD;
        const float* w1 = ff_w1 + (size_t)l * FFD * EMBD;
        const float* b1 = ff_b1 + (size_t)l * FFD;
        const float* w2 = ff_w2 + (size_t)l * EMBD * FFD;
        const float* b2 = ff_b2 + (size_t)l * EMBD;

        // convert this layer's big weights to bf16
        cvt_f2b<<<576, 256, 0, stream>>>(wproj, Wprojb);
        cvt_f2b<<<2304, 256, 0, stream>>>(w1, W1b);
        cvt_f2b<<<2304, 256, 0, stream>>>(w2, W2b);

        // kqv = x @ wkqv^T  (fp32), viewed as (B*T*H,96) x (288,96)^T
        gemm_abt<<<dim3(5, 512, 1), 256, 0, stream>>>(
            x, ESS, wkqv, ESS, kqvb, 288,
            BB * TT * HH, 288, ESS, 1.f, 0.f,
            1, 0, 0, 0, 0, 0, 0);

        // prev += Q K^T * scale  (fp32, batched over b,h — RealFormer carry)
        gemm_abt<<<dim3(8, 8, BB * HH), 256, 0, stream>>>(
            kqvb + ESS /*q*/, HH * 288, kqvb /*k*/, HH * 288, prev, TT,
            TT, TT, ESS, scale, 1.f,
            HH, (long)TT * HH * 288, 288, (long)TT * HH * 288, 288,
            (long)HH * TT * TT, (long)TT * TT);

        // Vt bf16 (must finish before softmax_rows overwrites the union)
        vt_cvt<<<12288, 256, 0, stream>>>(kqvb, Vtb);

        // P = softmax(prev) bf16 (overwrites kqv union region)
        softmax_rows<<<8192, 256, 0, stream>>>(prev, Pb);

        // attn = P @ V   (bf16 MFMA, batched; B operand = Vt (96 x 512))
        gemm_mfma<96, 4, 1, 1, 0, 0><<<dim3(1, 4, BB * HH), 256, 0, stream>>>(
            Pb, TT, Vtb, TT, attnb, EMBD, TT, nullptr,
            HH, (long)HH * TT * TT, (long)TT * TT,
            (long)HH * ESS * TT, (long)ESS * TT,
            (long)TT * EMBD, (long)ESS);

        // res = attn @ Wproj^T (fp32 out)
        gemm_mfma<64, 4, 1, 0, 0, 0><<<dim3(12, 32, 1), 256, 0, stream>>>(
            attnb, EMBD, Wprojb, EMBD, res, EMBD, EMBD, nullptr,
            1, 0, 0, 0, 0, 0, 0);

        // x = LN1(x + res), xb = bf16(x)
        add_ln<<<BB * TT, 256, 0, stream>>>(x, res,
            ln1_g + (size_t)l * EMBD, ln1_b + (size_t)l * EMBD, xb);

        // h1 = gelu(xb @ W1^T + b1)  bf16 out (overwrites union)
        gemm_mfma<128, 2, 2, 1, 1, 1><<<dim3(24, 32, 1), 256, 0, stream>>>(
            xb, EMBD, W1b, EMBD, h1b, FFD, EMBD, b1,
            1, 0, 0, 0, 0, 0, 0);

        // res = h1 @ W2^T + b2 (fp32 out)
        gemm_mfma<64, 4, 1, 0, 1, 0><<<dim3(12, 32, 1), 256, 0, stream>>>(
            h1b, FFD, W2b, FFD, res, EMBD, FFD, b2,
            1, 0, 0, 0, 0, 0, 0);

        // x = LN2(x + res), xb = bf16(x)
        add_ln<<<BB * TT, 256, 0, stream>>>(x, res,
            ln2_g + (size_t)l * EMBD, ln2_b + (size_t)l * EMBD, xb);
    }
}

// Round 3
// 1529.373 us; speedup vs baseline: 7.4081x; 1.1952x over previous
//
#include <hip/hip_runtime.h>
#include <math.h>

#define BB 8
#define TT 512
#define HH 8
#define ESS 96
#define EMBD 768
#define FFD 3072
#define NLAYER 6

typedef unsigned short ushort_t;
typedef __attribute__((ext_vector_type(8))) short short8;
typedef __attribute__((ext_vector_type(4))) float f32x4;
typedef __attribute__((ext_vector_type(4))) unsigned short ushort4v;

static __device__ __forceinline__ ushort_t f2b(float f) {
    unsigned u = __builtin_bit_cast(unsigned, f);
    unsigned r = (u + 0x7fffu + ((u >> 16) & 1u)) >> 16;
    return (ushort_t)r;
}

// ---------------------------------------------------------------------------
// bf16 MFMA GEMM: C = alpha * A(M,K) * B(N,K)^T (+beta*C) (+bias) (+gelu)
// BM=128, BK=32, 256 threads (4 waves, WM x WN wave grid).
// Staging via global_load_lds width 16 (linear LDS, K-major tiles).
// ---------------------------------------------------------------------------
template<int BN, int WM, int WN, int OUTBF, int HASBIAS, int GELU, int BETA>
__global__ __launch_bounds__(256) void gemm_mfma(
    const ushort_t* __restrict__ A, int lda,
    const ushort_t* __restrict__ B, int ldb,
    void* __restrict__ Cv, int ldc,
    int K, float alpha,
    const float* __restrict__ bias,
    int bdiv, long sAb, long sAh, long sBb, long sBh, long sCb, long sCh)
{
    constexpr int BM = 128, BK = 32;
    constexpr int WTM = BM / WM;
    constexpr int WTN = BN / WN;
    constexpr int MF = WTM / 16, NF = WTN / 16;
    constexpr int ACH = (BM * BK * 2) / 1024;   // 8
    constexpr int BCH = (BN * BK * 2) / 1024;   // 8 / 6 / 4

    const int z = blockIdx.z;
    const int zb = z / bdiv, zh = z % bdiv;
    A += (long)zb * sAb + (long)zh * sAh;
    B += (long)zb * sBb + (long)zh * sBh;
    const long coff = (long)zb * sCb + (long)zh * sCh;

    __shared__ ushort_t As[BM * BK];
    __shared__ ushort_t Bs[BN * BK];

    const int tid = threadIdx.x;
    const int w = tid >> 6, lane = tid & 63;
    const int wr = w / WN, wc = w % WN;
    const int m0 = blockIdx.y * BM;
    const int n0 = blockIdx.x * BN;

    f32x4 acc[MF][NF] = {};

    const int fr = lane & 15;     // fragment row (A) / col (B)
    const int kb = lane >> 4;     // k-block: k = kb*8 .. +7

    for (int k0 = 0; k0 < K; k0 += BK) {
        // ---- stage A tile [128][32] ----
#pragma unroll
        for (int q = 0; q < 2; ++q) {
            int ci = q * 4 + w;
            int e = ci * 512 + lane * 8;
            int r = e >> 5, c = e & 31;
            const ushort_t* gp = A + (long)(m0 + r) * lda + (k0 + c);
            __builtin_amdgcn_global_load_lds(
                (const __attribute__((address_space(1))) void*)gp,
                (__attribute__((address_space(3))) void*)((char*)As + ci * 1024),
                16, 0, 0);
        }
        // ---- stage B tile [BN][32] ----
#pragma unroll
        for (int q = 0; q < (BCH + 3) / 4; ++q) {
            int ci = q * 4 + w;
            if (ci < BCH) {
                int e = ci * 512 + lane * 8;
                int r = e >> 5, c = e & 31;
                const ushort_t* gp = B + (long)(n0 + r) * ldb + (k0 + c);
                __builtin_amdgcn_global_load_lds(
                    (const __attribute__((address_space(1))) void*)gp,
                    (__attribute__((address_space(3))) void*)((char*)Bs + ci * 1024),
                    16, 0, 0);
            }
        }
        __syncthreads();

        short8 af[MF], bfr[NF];
#pragma unroll
        for (int fm = 0; fm < MF; ++fm)
            af[fm] = *(const short8*)&As[(wr * WTM + fm * 16 + fr) * 32 + kb * 8];
#pragma unroll
        for (int fn = 0; fn < NF; ++fn)
            bfr[fn] = *(const short8*)&Bs[(wc * WTN + fn * 16 + fr) * 32 + kb * 8];
#pragma unroll
        for (int fm = 0; fm < MF; ++fm)
#pragma unroll
            for (int fn = 0; fn < NF; ++fn)
                acc[fm][fn] = __builtin_amdgcn_mfma_f32_16x16x32_bf16(
                    af[fm], bfr[fn], acc[fm][fn], 0, 0, 0);
        __syncthreads();
    }

    // ---- epilogue: C/D layout col = lane&15, row = (lane>>4)*4 + j ----
    const int cr = lane >> 4;
    const int cc = lane & 15;
#pragma unroll
    for (int fm = 0; fm < MF; ++fm) {
#pragma unroll
        for (int fn = 0; fn < NF; ++fn) {
#pragma unroll
            for (int j = 0; j < 4; ++j) {
                int gm = m0 + wr * WTM + fm * 16 + cr * 4 + j;
                int gn = n0 + wc * WTN + fn * 16 + cc;
                float v = alpha * acc[fm][fn][j];
                if (HASBIAS) v += bias[gn];
                if (GELU) v = 0.5f * v * (1.f + erff(v * 0.70710678118654752f));
                long idx = coff + (long)gm * ldc + gn;
                if (BETA) v += ((const float*)Cv)[idx];
                if (OUTBF) ((ushort_t*)Cv)[idx] = f2b(v);
                else       ((float*)Cv)[idx] = v;
            }
        }
    }
}

// ---------------------------------------------------------------------------
// Row softmax: one wave per 512-elem score row (fp32 in), bf16 out.
// ---------------------------------------------------------------------------
__global__ __launch_bounds__(256) void softmax_rows(
    const float* __restrict__ S, ushort_t* __restrict__ P)
{
    const long row = (long)blockIdx.x * 4 + (threadIdx.x >> 6);
    const int lane = threadIdx.x & 63;
    const float4* S4 = (const float4*)(S + row * TT);
    float4 a = S4[lane];
    float4 b = S4[lane + 64];
    float v[8] = {a.x, a.y, a.z, a.w, b.x, b.y, b.z, b.w};
    float mx = -1e30f;
#pragma unroll
    for (int i = 0; i < 8; ++i) mx = fmaxf(mx, v[i]);
    for (int o = 32; o; o >>= 1) mx = fmaxf(mx, __shfl_xor(mx, o));
    float sum = 0.f;
#pragma unroll
    for (int i = 0; i < 8; ++i) { v[i] = __expf(v[i] - mx); sum += v[i]; }
    for (int o = 32; o; o >>= 1) sum += __shfl_xor(sum, o);
    float inv = 1.f / sum;
    ushort4v o1 = {f2b(v[0] * inv), f2b(v[1] * inv), f2b(v[2] * inv), f2b(v[3] * inv)};
    ushort4v o2 = {f2b(v[4] * inv), f2b(v[5] * inv), f2b(v[6] * inv), f2b(v[7] * inv)};
    ushort4v* P4 = (ushort4v*)(P + row * TT);
    P4[lane] = o1;
    P4[lane + 64] = o2;
}

// ---------------------------------------------------------------------------
// Extract V from interleaved bf16 kqv, write V^T: Vt[((b,h),s),t]
// ---------------------------------------------------------------------------
__global__ __launch_bounds__(256) void vt_cvt(
    const ushort_t* __restrict__ kqv, ushort_t* __restrict__ Vt)
{
    const int idx = blockIdx.x * 256 + threadIdx.x;   // B*H*96*512 total
    const int t = idx & 511;
    const int rest = idx >> 9;
    const int s = rest % ESS;
    const int bh = rest / ESS;
    const int h = bh & 7, b = bh >> 3;
    Vt[idx] = kqv[(((long)(b * TT + t) * HH + h) * 288) + 192 + s];
}

// ---------------------------------------------------------------------------
// fp32 -> bf16 convert, 4 elems/thread
// ---------------------------------------------------------------------------
__global__ __launch_bounds__(256) void cvt_f2b(
    const float* __restrict__ in, ushort_t* __restrict__ out)
{
    const int i = blockIdx.x * 256 + threadIdx.x;
    float4 v = ((const float4*)in)[i];
    ushort4v o = {f2b(v.x), f2b(v.y), f2b(v.z), f2b(v.w)};
    ((ushort4v*)out)[i] = o;
}

// ---------------------------------------------------------------------------
// x = LayerNorm(x + res) * g + b ; also emit bf16 copy. 192 thr, float4/thread
// ---------------------------------------------------------------------------
__global__ __launch_bounds__(192) void add_ln(
    float* __restrict__ x, const float* __restrict__ res,
    const float* __restrict__ g, const float* __restrict__ bta,
    ushort_t* __restrict__ xb)
{
    const long row = blockIdx.x;
    float4* xr = (float4*)(x + row * EMBD);
    const float4* rr = (const float4*)(res + row * EMBD);
    __shared__ float sh[4];
    const int tid = threadIdx.x;
    const int lane = tid & 63, w = tid >> 6;

    float4 a = xr[tid], r = rr[tid];
    float v[4] = {a.x + r.x, a.y + r.y, a.z + r.z, a.w + r.w};
    float s = v[0] + v[1] + v[2] + v[3];
    for (int o = 32; o; o >>= 1) s += __shfl_xor(s, o);
    if (lane == 0) sh[w] = s;
    __syncthreads();
    float mu = (sh[0] + sh[1] + sh[2]) * (1.f / EMBD);

    float var = 0.f;
#pragma unroll
    for (int c = 0; c < 4; ++c) { float d = v[c] - mu; var += d * d; }
    for (int o = 32; o; o >>= 1) var += __shfl_xor(var, o);
    __syncthreads();
    if (lane == 0) sh[w] = var;
    __syncthreads();
    var = (sh[0] + sh[1] + sh[2]) * (1.f / EMBD);
    float rstd = rsqrtf(var + 1e-5f);

    const float4 g4 = ((const float4*)g)[tid];
    const float4 b4 = ((const float4*)bta)[tid];
    float o0 = (v[0] - mu) * rstd * g4.x + b4.x;
    float o1 = (v[1] - mu) * rstd * g4.y + b4.y;
    float o2 = (v[2] - mu) * rstd * g4.z + b4.z;
    float o3 = (v[3] - mu) * rstd * g4.w + b4.w;
    float4 ov = {o0, o1, o2, o3};
    xr[tid] = ov;
    ushort4v ob = {f2b(o0), f2b(o1), f2b(o2), f2b(o3)};
    ((ushort4v*)(xb + row * EMBD))[tid] = ob;
}

// ---------------------------------------------------------------------------
extern "C" void kernel_launch(void* const* d_in, const int* in_sizes, int n_in,
                              void* d_out, int out_size, void* d_ws, size_t ws_size,
                              hipStream_t stream) {
    const float* x_in  = (const float*)d_in[0];
    const float* Wkqv  = (const float*)d_in[1];
    const float* Wproj = (const float*)d_in[2];
    const float* ln1_g = (const float*)d_in[3];
    const float* ln1_b = (const float*)d_in[4];
    const float* ln2_g = (const float*)d_in[5];
    const float* ln2_b = (const float*)d_in[6];
    const float* ff_w1 = (const float*)d_in[7];
    const float* ff_b1 = (const float*)d_in[8];
    const float* ff_w2 = (const float*)d_in[9];
    const float* ff_b2 = (const float*)d_in[10];

    float* x = (float*)d_out;                 // running activations (B,T,EMB) fp32
    char* ws = (char*)d_ws;
    // layout (bytes), unions: res∪kqvb, h1b∪Pb
    float*    prev   = (float*)(ws);                      // 64 MiB (B*H,T,T) fp32
    ushort_t* kqvb   = (ushort_t*)(ws + 67108864);        // 18 MiB (B,T,H,288) bf16
    float*    res    = (float*)(ws + 67108864);           // union w/ kqvb, 12 MiB
    ushort_t* Pb     = (ushort_t*)(ws + 85983232);        // 32 MiB (B*H,T,T) bf16
    ushort_t* h1b    = (ushort_t*)(ws + 85983232);        // union w/ Pb, 24 MiB
    ushort_t* xb     = (ushort_t*)(ws + 119537664);       // 6 MiB (B,T,EMB) bf16
    ushort_t* attnb  = (ushort_t*)(ws + 125829120);       // 6 MiB (B,T,EMB) bf16
    ushort_t* Vtb    = (ushort_t*)(ws + 132120576);       // 6 MiB (B,H,96,T) bf16
    ushort_t* Wkqvb  = (ushort_t*)(ws + 138412032);       // 54 KiB
    ushort_t* Wprojb = (ushort_t*)(ws + 138467328);       // 1.125 MiB
    ushort_t* W1b    = (ushort_t*)(ws + 139646976);       // 4.5 MiB
    ushort_t* W2b    = (ushort_t*)(ws + 144365568);       // 4.5 MiB (end ~142.2 MiB)

    hipMemcpyAsync(x, x_in, (size_t)BB * TT * EMBD * sizeof(float),
                   hipMemcpyDeviceToDevice, stream);
    hipMemsetAsync(prev, 0, (size_t)BB * HH * TT * TT * sizeof(float), stream);
    // xb for layer 0
    cvt_f2b<<<3072, 256, 0, stream>>>(x_in, xb);

    const float scale = 0.10206207261596577f;  // 1/sqrt(96)

    for (int l = 0; l < NLAYER; ++l) {
        const float* wkqv  = Wkqv + (size_t)l * 3 * ESS * ESS;
        const float* wproj = Wproj + (size_t)l * EMBD * EMBD;
        const float* w1 = ff_w1 + (size_t)l * FFD * EMBD;
        const float* b1 = ff_b1 + (size_t)l * FFD;
        const float* w2 = ff_w2 + (size_t)l * EMBD * FFD;
        const float* b2 = ff_b2 + (size_t)l * EMBD;

        // weights -> bf16
        cvt_f2b<<<27, 256, 0, stream>>>(wkqv, Wkqvb);
        cvt_f2b<<<576, 256, 0, stream>>>(wproj, Wprojb);
        cvt_f2b<<<2304, 256, 0, stream>>>(w1, W1b);
        cvt_f2b<<<2304, 256, 0, stream>>>(w2, W2b);

        // kqv = xh @ wkqv^T : A=(B*T*H,96) bf16, B=(288,96) bf16 -> bf16 (B,T,H,288)
        gemm_mfma<96, 4, 1, 1, 0, 0, 0><<<dim3(3, 256, 1), 256, 0, stream>>>(
            xb, ESS, Wkqvb, ESS, kqvb, 288, ESS, 1.f, nullptr,
            1, 0, 0, 0, 0, 0, 0);

        // prev = scale * Q K^T + prev  (batched over b,h; fp32 in-place)
        gemm_mfma<128, 2, 2, 0, 0, 0, 1><<<dim3(4, 4, BB * HH), 256, 0, stream>>>(
            kqvb + ESS /*q*/, HH * 288, kqvb /*k*/, HH * 288, prev, TT, ESS, scale, nullptr,
            HH, (long)TT * HH * 288, 288, (long)TT * HH * 288, 288,
            (long)HH * TT * TT, (long)TT * TT);

        // Vt bf16
        vt_cvt<<<12288, 256, 0, stream>>>(kqvb, Vtb);

        // P = softmax(prev) bf16 (h1 union region — h1 is dead here)
        softmax_rows<<<8192, 256, 0, stream>>>(prev, Pb);

        // attn = P @ V  (batched)
        gemm_mfma<96, 4, 1, 1, 0, 0, 0><<<dim3(1, 4, BB * HH), 256, 0, stream>>>(
            Pb, TT, Vtb, TT, attnb, EMBD, TT, 1.f, nullptr,
            HH, (long)HH * TT * TT, (long)TT * TT,
            (long)HH * ESS * TT, (long)ESS * TT,
            (long)TT * EMBD, (long)ESS);

        // res = attn @ Wproj^T (fp32 out; overwrites kqvb union — kqv dead)
        gemm_mfma<128, 2, 2, 0, 0, 0, 0><<<dim3(6, 32, 1), 256, 0, stream>>>(
            attnb, EMBD, Wprojb, EMBD, res, EMBD, EMBD, 1.f, nullptr,
            1, 0, 0, 0, 0, 0, 0);

        // x = LN1(x + res), xb = bf16(x)
        add_ln<<<BB * TT, 192, 0, stream>>>(x, res,
            ln1_g + (size_t)l * EMBD, ln1_b + (size_t)l * EMBD, xb);

        // h1 = gelu(xb @ W1^T + b1) bf16 (Pb union — P dead)
        gemm_mfma<128, 2, 2, 1, 1, 1, 0><<<dim3(24, 32, 1), 256, 0, stream>>>(
            xb, EMBD, W1b, EMBD, h1b, FFD, EMBD, 1.f, b1,
            1, 0, 0, 0, 0, 0, 0);

        // res = h1 @ W2^T + b2 (fp32 out)
        gemm_mfma<128, 2, 2, 0, 1, 0, 0><<<dim3(6, 32, 1), 256, 0, stream>>>(
            h1b, FFD, W2b, FFD, res, EMBD, FFD, 1.f, b2,
            1, 0, 0, 0, 0, 0, 0);

        // x = LN2(x + res), xb = bf16(x)
        add_ln<<<BB * TT, 192, 0, stream>>>(x, res,
            ln2_g + (size_t)l * EMBD, ln2_b + (size_t)l * EMBD, xb);
    }
}

// Round 4
// 1355.551 us; speedup vs baseline: 8.3581x; 1.1282x over previous
//
#include <hip/hip_runtime.h>
#include <math.h>

#define BB 8
#define TT 512
#define HH 8
#define ESS 96
#define EMBD 768
#define FFD 3072
#define NLAYER 6

typedef unsigned short ushort_t;
typedef __attribute__((ext_vector_type(8))) short short8;
typedef __attribute__((ext_vector_type(4))) float f32x4;
typedef __attribute__((ext_vector_type(4))) unsigned short ushort4v;

static __device__ __forceinline__ ushort_t f2b(float f) {
    unsigned u = __builtin_bit_cast(unsigned, f);
    unsigned r = (u + 0x7fffu + ((u >> 16) & 1u)) >> 16;
    return (ushort_t)r;
}

// ---------------------------------------------------------------------------
// bf16 MFMA GEMM: C = alpha * A(M,K) * B(N,K)^T (+beta*C) (+bias) (+gelu)
// BK=32, 256 threads (4 waves, WM x WN wave grid). Templated BM/BN.
// Staging via global_load_lds width 16 (linear LDS, K-major tiles).
// Split-K usable via z-strides (sAb/sBb = K-offset, sCb = partial-buf offset).
// ---------------------------------------------------------------------------
template<int BM, int BN, int WM, int WN, int OUTBF, int HASBIAS, int GELU, int BETA>
__global__ __launch_bounds__(256) void gemm_mfma(
    const ushort_t* __restrict__ A, int lda,
    const ushort_t* __restrict__ B, int ldb,
    void* __restrict__ Cv, int ldc,
    int K, float alpha,
    const float* __restrict__ bias,
    int bdiv, long sAb, long sAh, long sBb, long sBh, long sCb, long sCh)
{
    constexpr int BK = 32;
    constexpr int WTM = BM / WM;
    constexpr int WTN = BN / WN;
    constexpr int MF = WTM / 16, NF = WTN / 16;
    constexpr int ACH = (BM * BK * 2) / 1024;   // 1 KiB chunks
    constexpr int BCH = (BN * BK * 2) / 1024;

    const int z = blockIdx.z;
    const int zb = z / bdiv, zh = z % bdiv;
    A += (long)zb * sAb + (long)zh * sAh;
    B += (long)zb * sBb + (long)zh * sBh;
    const long coff = (long)zb * sCb + (long)zh * sCh;

    __shared__ ushort_t As[BM * BK];
    __shared__ ushort_t Bs[BN * BK];

    const int tid = threadIdx.x;
    const int w = tid >> 6, lane = tid & 63;
    const int wr = w / WN, wc = w % WN;
    const int m0 = blockIdx.y * BM;
    const int n0 = blockIdx.x * BN;

    f32x4 acc[MF][NF] = {};

    const int fr = lane & 15;     // fragment row (A) / col (B)
    const int kb = lane >> 4;     // k-block: k = kb*8 .. +7

    for (int k0 = 0; k0 < K; k0 += BK) {
        // ---- stage A tile [BM][32] ----
#pragma unroll
        for (int q = 0; q < (ACH + 3) / 4; ++q) {
            int ci = q * 4 + w;
            if (ci < ACH) {
                int e = ci * 512 + lane * 8;
                int r = e >> 5, c = e & 31;
                const ushort_t* gp = A + (long)(m0 + r) * lda + (k0 + c);
                __builtin_amdgcn_global_load_lds(
                    (const __attribute__((address_space(1))) void*)gp,
                    (__attribute__((address_space(3))) void*)((char*)As + ci * 1024),
                    16, 0, 0);
            }
        }
        // ---- stage B tile [BN][32] ----
#pragma unroll
        for (int q = 0; q < (BCH + 3) / 4; ++q) {
            int ci = q * 4 + w;
            if (ci < BCH) {
                int e = ci * 512 + lane * 8;
                int r = e >> 5, c = e & 31;
                const ushort_t* gp = B + (long)(n0 + r) * ldb + (k0 + c);
                __builtin_amdgcn_global_load_lds(
                    (const __attribute__((address_space(1))) void*)gp,
                    (__attribute__((address_space(3))) void*)((char*)Bs + ci * 1024),
                    16, 0, 0);
            }
        }
        __syncthreads();

        short8 af[MF], bfr[NF];
#pragma unroll
        for (int fm = 0; fm < MF; ++fm)
            af[fm] = *(const short8*)&As[(wr * WTM + fm * 16 + fr) * 32 + kb * 8];
#pragma unroll
        for (int fn = 0; fn < NF; ++fn)
            bfr[fn] = *(const short8*)&Bs[(wc * WTN + fn * 16 + fr) * 32 + kb * 8];
#pragma unroll
        for (int fm = 0; fm < MF; ++fm)
#pragma unroll
            for (int fn = 0; fn < NF; ++fn)
                acc[fm][fn] = __builtin_amdgcn_mfma_f32_16x16x32_bf16(
                    af[fm], bfr[fn], acc[fm][fn], 0, 0, 0);
        __syncthreads();
    }

    // ---- epilogue: C/D layout col = lane&15, row = (lane>>4)*4 + j ----
    const int cr = lane >> 4;
    const int cc = lane & 15;
#pragma unroll
    for (int fm = 0; fm < MF; ++fm) {
#pragma unroll
        for (int fn = 0; fn < NF; ++fn) {
#pragma unroll
            for (int j = 0; j < 4; ++j) {
                int gm = m0 + wr * WTM + fm * 16 + cr * 4 + j;
                int gn = n0 + wc * WTN + fn * 16 + cc;
                float v = alpha * acc[fm][fn][j];
                if (HASBIAS) v += bias[gn];
                if (GELU) v = 0.5f * v * (1.f + erff(v * 0.70710678118654752f));
                long idx = coff + (long)gm * ldc + gn;
                if (BETA) v += ((const float*)Cv)[idx];
                if (OUTBF) ((ushort_t*)Cv)[idx] = f2b(v);
                else       ((float*)Cv)[idx] = v;
            }
        }
    }
}

// ---------------------------------------------------------------------------
// Merged: row softmax (blocks 0..8191) + V^T extract (blocks 8192..20479)
// softmax: one wave per 512-elem fp32 score row -> bf16 P
// vt: Vt[((b,h),s),t] = kqv bf16 V part
// ---------------------------------------------------------------------------
__global__ __launch_bounds__(256) void softmax_vt(
    const float* __restrict__ S, ushort_t* __restrict__ P,
    const ushort_t* __restrict__ kqv, ushort_t* __restrict__ Vt)
{
    if (blockIdx.x < 8192) {
        const long row = (long)blockIdx.x * 4 + (threadIdx.x >> 6);
        const int lane = threadIdx.x & 63;
        const float4* S4 = (const float4*)(S + row * TT);
        float4 a = S4[lane];
        float4 b = S4[lane + 64];
        float v[8] = {a.x, a.y, a.z, a.w, b.x, b.y, b.z, b.w};
        float mx = -1e30f;
#pragma unroll
        for (int i = 0; i < 8; ++i) mx = fmaxf(mx, v[i]);
        for (int o = 32; o; o >>= 1) mx = fmaxf(mx, __shfl_xor(mx, o));
        float sum = 0.f;
#pragma unroll
        for (int i = 0; i < 8; ++i) { v[i] = __expf(v[i] - mx); sum += v[i]; }
        for (int o = 32; o; o >>= 1) sum += __shfl_xor(sum, o);
        float inv = 1.f / sum;
        ushort4v o1 = {f2b(v[0] * inv), f2b(v[1] * inv), f2b(v[2] * inv), f2b(v[3] * inv)};
        ushort4v o2 = {f2b(v[4] * inv), f2b(v[5] * inv), f2b(v[6] * inv), f2b(v[7] * inv)};
        ushort4v* P4 = (ushort4v*)(P + row * TT);
        P4[lane] = o1;
        P4[lane + 64] = o2;
    } else {
        const int idx = (blockIdx.x - 8192) * 256 + threadIdx.x;  // B*H*96*512
        const int t = idx & 511;
        const int rest = idx >> 9;
        const int s = rest % ESS;
        const int bh = rest / ESS;
        const int h = bh & 7, b = bh >> 3;
        Vt[idx] = kqv[(((long)(b * TT + t) * HH + h) * 288) + 192 + s];
    }
}

// ---------------------------------------------------------------------------
// fp32 -> bf16 convert, 4 elems/thread (x only)
// ---------------------------------------------------------------------------
__global__ __launch_bounds__(256) void cvt_f2b(
    const float* __restrict__ in, ushort_t* __restrict__ out)
{
    const int i = blockIdx.x * 256 + threadIdx.x;
    float4 v = ((const float4*)in)[i];
    ushort4v o = {f2b(v.x), f2b(v.y), f2b(v.z), f2b(v.w)};
    ((ushort4v*)out)[i] = o;
}

// ---------------------------------------------------------------------------
// One-launch per-layer weight conversion (wkqv | wproj | w1 | w2)
// float4 regions (elems/4): 6912 | 147456 | 589824 | 589824  -> 1334016 thr
// ---------------------------------------------------------------------------
__global__ __launch_bounds__(256) void cvt_weights(
    const float* __restrict__ wkqv, const float* __restrict__ wproj,
    const float* __restrict__ w1, const float* __restrict__ w2,
    ushort_t* __restrict__ owkqv, ushort_t* __restrict__ owproj,
    ushort_t* __restrict__ ow1, ushort_t* __restrict__ ow2)
{
    int i4 = blockIdx.x * 256 + threadIdx.x;
    const float* src; ushort_t* dst; int base;
    if (i4 < 6912)        { src = wkqv;  dst = owkqv;  base = 0; }
    else if (i4 < 154368) { src = wproj; dst = owproj; base = 6912; }
    else if (i4 < 744192) { src = w1;    dst = ow1;    base = 154368; }
    else                  { src = w2;    dst = ow2;    base = 744192; }
    int j = i4 - base;
    float4 v = ((const float4*)src)[j];
    ushort4v o = {f2b(v.x), f2b(v.y), f2b(v.z), f2b(v.w)};
    ((ushort4v*)dst)[j] = o;
}

// ---------------------------------------------------------------------------
// x = LayerNorm(x + r0 + r1 (+bias)) * g + b ; also emit bf16 copy.
// 192 thr, float4/thread
// ---------------------------------------------------------------------------
__global__ __launch_bounds__(192) void add_ln(
    float* __restrict__ x, const float* __restrict__ r0,
    const float* __restrict__ r1, const float* __restrict__ bias,
    const float* __restrict__ g, const float* __restrict__ bta,
    ushort_t* __restrict__ xb)
{
    const long row = blockIdx.x;
    float4* xr = (float4*)(x + row * EMBD);
    const float4* q0 = (const float4*)(r0 + row * EMBD);
    const float4* q1 = (const float4*)(r1 + row * EMBD);
    __shared__ float sh[4];
    const int tid = threadIdx.x;
    const int lane = tid & 63, w = tid >> 6;

    float4 a = xr[tid], u0 = q0[tid], u1 = q1[tid];
    float v[4] = {a.x + u0.x + u1.x, a.y + u0.y + u1.y,
                  a.z + u0.z + u1.z, a.w + u0.w + u1.w};
    if (bias) {
        float4 b4 = ((const float4*)bias)[tid];
        v[0] += b4.x; v[1] += b4.y; v[2] += b4.z; v[3] += b4.w;
    }
    float s = v[0] + v[1] + v[2] + v[3];
    for (int o = 32; o; o >>= 1) s += __shfl_xor(s, o);
    if (lane == 0) sh[w] = s;
    __syncthreads();
    float mu = (sh[0] + sh[1] + sh[2]) * (1.f / EMBD);

    float var = 0.f;
#pragma unroll
    for (int c = 0; c < 4; ++c) { float d = v[c] - mu; var += d * d; }
    for (int o = 32; o; o >>= 1) var += __shfl_xor(var, o);
    __syncthreads();
    if (lane == 0) sh[w] = var;
    __syncthreads();
    var = (sh[0] + sh[1] + sh[2]) * (1.f / EMBD);
    float rstd = rsqrtf(var + 1e-5f);

    const float4 g4 = ((const float4*)g)[tid];
    const float4 b4 = ((const float4*)bta)[tid];
    float o0 = (v[0] - mu) * rstd * g4.x + b4.x;
    float o1 = (v[1] - mu) * rstd * g4.y + b4.y;
    float o2 = (v[2] - mu) * rstd * g4.z + b4.z;
    float o3 = (v[3] - mu) * rstd * g4.w + b4.w;
    float4 ov = {o0, o1, o2, o3};
    xr[tid] = ov;
    ushort4v ob = {f2b(o0), f2b(o1), f2b(o2), f2b(o3)};
    ((ushort4v*)(xb + row * EMBD))[tid] = ob;
}

// ---------------------------------------------------------------------------
extern "C" void kernel_launch(void* const* d_in, const int* in_sizes, int n_in,
                              void* d_out, int out_size, void* d_ws, size_t ws_size,
                              hipStream_t stream) {
    const float* x_in  = (const float*)d_in[0];
    const float* Wkqv  = (const float*)d_in[1];
    const float* Wproj = (const float*)d_in[2];
    const float* ln1_g = (const float*)d_in[3];
    const float* ln1_b = (const float*)d_in[4];
    const float* ln2_g = (const float*)d_in[5];
    const float* ln2_b = (const float*)d_in[6];
    const float* ff_w1 = (const float*)d_in[7];
    const float* ff_b1 = (const float*)d_in[8];
    const float* ff_w2 = (const float*)d_in[9];
    const float* ff_b2 = (const float*)d_in[10];

    float* x = (float*)d_out;                 // running activations (B,T,EMB) fp32
    char* ws = (char*)d_ws;
    // layout (MiB): prev[0,64) | U1[64,88): kqvb(18)+Vtb(6) / res0(12)+res1(12)
    //               U2[88,120): Pb(32)/h1b(24) | xb[120,126) | attnb[126,132)
    //               weights [132,142.2)
    float*    prev   = (float*)(ws);                      // 64 MiB (B*H,T,T) fp32
    ushort_t* kqvb   = (ushort_t*)(ws + 67108864);        // 18 MiB (B,T,H,288) bf16
    ushort_t* Vtb    = (ushort_t*)(ws + 85983232);        // 6 MiB (B,H,96,T) bf16
    float*    res0   = (float*)(ws + 67108864);           // 12 MiB fp32 (union kqvb)
    float*    res1   = (float*)(ws + 79691776);           // 12 MiB fp32 (union kqvb/Vtb)
    ushort_t* Pb     = (ushort_t*)(ws + 92274688);        // 32 MiB (B*H,T,T) bf16
    ushort_t* h1b    = (ushort_t*)(ws + 92274688);        // union w/ Pb, 24 MiB
    ushort_t* xb     = (ushort_t*)(ws + 125829120);       // 6 MiB (B,T,EMB) bf16
    ushort_t* attnb  = (ushort_t*)(ws + 132120576);       // 6 MiB (B,T,EMB) bf16
    ushort_t* Wkqvb  = (ushort_t*)(ws + 138412032);       // 54 KiB
    ushort_t* Wprojb = (ushort_t*)(ws + 138467328);       // 1.125 MiB
    ushort_t* W1b    = (ushort_t*)(ws + 139646976);       // 4.5 MiB
    ushort_t* W2b    = (ushort_t*)(ws + 144365568);       // 4.5 MiB (end ~142.2 MiB)

    hipMemcpyAsync(x, x_in, (size_t)BB * TT * EMBD * sizeof(float),
                   hipMemcpyDeviceToDevice, stream);
    hipMemsetAsync(prev, 0, (size_t)BB * HH * TT * TT * sizeof(float), stream);
    cvt_f2b<<<3072, 256, 0, stream>>>(x_in, xb);

    const float scale = 0.10206207261596577f;  // 1/sqrt(96)

    for (int l = 0; l < NLAYER; ++l) {
        const float* wkqv  = Wkqv + (size_t)l * 3 * ESS * ESS;
        const float* wproj = Wproj + (size_t)l * EMBD * EMBD;
        const float* w1 = ff_w1 + (size_t)l * FFD * EMBD;
        const float* b1 = ff_b1 + (size_t)l * FFD;
        const float* w2 = ff_w2 + (size_t)l * EMBD * FFD;
        const float* b2 = ff_b2 + (size_t)l * EMBD;

        // all 4 weight tensors -> bf16, one launch
        cvt_weights<<<5211, 256, 0, stream>>>(wkqv, wproj, w1, w2,
                                              Wkqvb, Wprojb, W1b, W2b);

        // kqv = xh @ wkqv^T : A=(B*T*H,96) bf16 -> bf16 (B,T,H,288)
        gemm_mfma<128, 96, 4, 1, 1, 0, 0, 0><<<dim3(3, 256, 1), 256, 0, stream>>>(
            xb, ESS, Wkqvb, ESS, kqvb, 288, ESS, 1.f, nullptr,
            1, 0, 0, 0, 0, 0, 0);

        // prev = scale * Q K^T + prev  (batched over b,h; fp32 in-place)
        gemm_mfma<128, 128, 2, 2, 0, 0, 0, 1><<<dim3(4, 4, BB * HH), 256, 0, stream>>>(
            kqvb + ESS /*q*/, HH * 288, kqvb /*k*/, HH * 288, prev, TT, ESS, scale, nullptr,
            HH, (long)TT * HH * 288, 288, (long)TT * HH * 288, 288,
            (long)HH * TT * TT, (long)TT * TT);

        // P = softmax(prev) bf16 + Vt extract (one launch)
        softmax_vt<<<20480, 256, 0, stream>>>(prev, Pb, kqvb, Vtb);

        // attn = P @ V  (batched, BM=64 for occupancy)
        gemm_mfma<64, 96, 2, 2, 1, 0, 0, 0><<<dim3(1, 8, BB * HH), 256, 0, stream>>>(
            Pb, TT, Vtb, TT, attnb, EMBD, TT, 1.f, nullptr,
            HH, (long)HH * TT * TT, (long)TT * TT,
            (long)HH * ESS * TT, (long)ESS * TT,
            (long)TT * EMBD, (long)ESS);

        // res0/res1 = attn @ Wproj^T split-K (z = k-half; kqvb/Vtb dead)
        gemm_mfma<128, 128, 2, 2, 0, 0, 0, 0><<<dim3(6, 32, 2), 256, 0, stream>>>(
            attnb, EMBD, Wprojb, EMBD, res0, EMBD, EMBD / 2, 1.f, nullptr,
            1, 384, 0, 384, 0, (long)(res1 - res0), 0);

        // x = LN1(x + res0 + res1), xb = bf16(x)
        add_ln<<<BB * TT, 192, 0, stream>>>(x, res0, res1, nullptr,
            ln1_g + (size_t)l * EMBD, ln1_b + (size_t)l * EMBD, xb);

        // h1 = gelu(xb @ W1^T + b1) bf16 (Pb union — P dead)
        gemm_mfma<128, 128, 2, 2, 1, 1, 1, 0><<<dim3(24, 32, 1), 256, 0, stream>>>(
            xb, EMBD, W1b, EMBD, h1b, FFD, EMBD, 1.f, b1,
            1, 0, 0, 0, 0, 0, 0);

        // res0/res1 = h1 @ W2^T split-K (b2 applied in ln2)
        gemm_mfma<128, 128, 2, 2, 0, 0, 0, 0><<<dim3(6, 32, 2), 256, 0, stream>>>(
            h1b, FFD, W2b, FFD, res0, EMBD, FFD / 2, 1.f, nullptr,
            1, 1536, 0, 1536, 0, (long)(res1 - res0), 0);

        // x = LN2(x + res0 + res1 + b2), xb = bf16(x)
        add_ln<<<BB * TT, 192, 0, stream>>>(x, res0, res1, b2,
            ln2_g + (size_t)l * EMBD, ln2_b + (size_t)l * EMBD, xb);
    }
}

// Round 5
// 1306.585 us; speedup vs baseline: 8.6713x; 1.0375x over previous
//
#include <hip/hip_runtime.h>
#include <math.h>

#define BB 8
#define TT 512
#define HH 8
#define ESS 96
#define EMBD 768
#define FFD 3072
#define NLAYER 6

typedef unsigned short ushort_t;
typedef __attribute__((ext_vector_type(8))) short short8;
typedef __attribute__((ext_vector_type(4))) float f32x4;
typedef __attribute__((ext_vector_type(4))) unsigned short ushort4v;

static __device__ __forceinline__ ushort_t f2b(float f) {
    unsigned u = __builtin_bit_cast(unsigned, f);
    unsigned r = (u + 0x7fffu + ((u >> 16) & 1u)) >> 16;
    return (ushort_t)r;
}

#define GLDS(gp, lp) __builtin_amdgcn_global_load_lds( \
    (const __attribute__((address_space(1))) void*)(gp), \
    (__attribute__((address_space(3))) void*)(lp), 16, 0, 0)

// ---------------------------------------------------------------------------
// bf16 MFMA GEMM: C = alpha * A(M,K) * B(N,K)^T (+beta*C) (+bias) (+gelu)
// BK=32, 256 threads (4 waves, WM x WN wave grid). Templated BM/BN.
// ---------------------------------------------------------------------------
template<int BM, int BN, int WM, int WN, int OUTBF, int HASBIAS, int GELU, int BETA>
__global__ __launch_bounds__(256) void gemm_mfma(
    const ushort_t* __restrict__ A, int lda,
    const ushort_t* __restrict__ B, int ldb,
    void* __restrict__ Cv, int ldc,
    int K, float alpha,
    const float* __restrict__ bias,
    int bdiv, long sAb, long sAh, long sBb, long sBh, long sCb, long sCh)
{
    constexpr int BK = 32;
    constexpr int WTM = BM / WM;
    constexpr int WTN = BN / WN;
    constexpr int MF = WTM / 16, NF = WTN / 16;
    constexpr int ACH = (BM * BK * 2) / 1024;
    constexpr int BCH = (BN * BK * 2) / 1024;

    const int z = blockIdx.z;
    const int zb = z / bdiv, zh = z % bdiv;
    A += (long)zb * sAb + (long)zh * sAh;
    B += (long)zb * sBb + (long)zh * sBh;
    const long coff = (long)zb * sCb + (long)zh * sCh;

    __shared__ ushort_t As[BM * BK];
    __shared__ ushort_t Bs[BN * BK];

    const int tid = threadIdx.x;
    const int w = tid >> 6, lane = tid & 63;
    const int wr = w / WN, wc = w % WN;
    const int m0 = blockIdx.y * BM;
    const int n0 = blockIdx.x * BN;

    f32x4 acc[MF][NF] = {};

    const int fr = lane & 15;
    const int kb = lane >> 4;

    for (int k0 = 0; k0 < K; k0 += BK) {
#pragma unroll
        for (int q = 0; q < (ACH + 3) / 4; ++q) {
            int ci = q * 4 + w;
            if (ci < ACH) {
                int e = ci * 512 + lane * 8;
                int r = e >> 5, c = e & 31;
                GLDS(A + (long)(m0 + r) * lda + (k0 + c), (char*)As + ci * 1024);
            }
        }
#pragma unroll
        for (int q = 0; q < (BCH + 3) / 4; ++q) {
            int ci = q * 4 + w;
            if (ci < BCH) {
                int e = ci * 512 + lane * 8;
                int r = e >> 5, c = e & 31;
                GLDS(B + (long)(n0 + r) * ldb + (k0 + c), (char*)Bs + ci * 1024);
            }
        }
        __syncthreads();

        short8 af[MF], bfr[NF];
#pragma unroll
        for (int fm = 0; fm < MF; ++fm)
            af[fm] = *(const short8*)&As[(wr * WTM + fm * 16 + fr) * 32 + kb * 8];
#pragma unroll
        for (int fn = 0; fn < NF; ++fn)
            bfr[fn] = *(const short8*)&Bs[(wc * WTN + fn * 16 + fr) * 32 + kb * 8];
#pragma unroll
        for (int fm = 0; fm < MF; ++fm)
#pragma unroll
            for (int fn = 0; fn < NF; ++fn)
                acc[fm][fn] = __builtin_amdgcn_mfma_f32_16x16x32_bf16(
                    af[fm], bfr[fn], acc[fm][fn], 0, 0, 0);
        __syncthreads();
    }

    const int cr = lane >> 4;
    const int cc = lane & 15;
#pragma unroll
    for (int fm = 0; fm < MF; ++fm) {
#pragma unroll
        for (int fn = 0; fn < NF; ++fn) {
#pragma unroll
            for (int j = 0; j < 4; ++j) {
                int gm = m0 + wr * WTM + fm * 16 + cr * 4 + j;
                int gn = n0 + wc * WTN + fn * 16 + cc;
                float v = alpha * acc[fm][fn][j];
                if (HASBIAS) v += bias[gn];
                if (GELU) v = 0.5f * v * (1.f + erff(v * 0.70710678118654752f));
                long idx = coff + (long)gm * ldc + gn;
                if (BETA) v += ((const float*)Cv)[idx];
                if (OUTBF) ((ushort_t*)Cv)[idx] = f2b(v);
                else       ((float*)Cv)[idx] = v;
            }
        }
    }
}

// ---------------------------------------------------------------------------
// Fused attention: per block = one (b,h) and 32 query rows.
//   S = scale*QK^T (+prev) ; prev = S (raw) ; P = softmax(S) -> LDS (swizzled)
//   attn = P @ V  (V^T staged from Vt)
// 256 threads. prev touched exactly once R+W.
// ---------------------------------------------------------------------------
__global__ __launch_bounds__(256) void fused_attn(
    const ushort_t* __restrict__ kqv,   // (B,T,H,288) bf16
    float* __restrict__ prev,           // (B*H,T,T) fp32
    const ushort_t* __restrict__ Vt,    // (B*H,96,T) bf16
    ushort_t* __restrict__ attn,        // (B,T,EMB) bf16
    float scale, int addprev, int writeprev)
{
    __shared__ char lds[40960];
    ushort_t* As = (ushort_t*)lds;              // 2 KiB: Q tile 32x32
    ushort_t* Bs = (ushort_t*)(lds + 2048);     // 32 KiB: K tile 512x32
    ushort_t* Pt = (ushort_t*)(lds + 2048);     // union: P 32x512 bf16 (swizzled)
    ushort_t* Vs = (ushort_t*)(lds + 34816);    // 6 KiB: V^T chunk 96x32
    float* red   = (float*)(lds + 34816);       // 512 B (union w/ Vs, used earlier)
    float* red2  = (float*)(lds + 35328);       // 512 B

    const int bh = blockIdx.z;
    const int b = bh >> 3, h = bh & 7;
    const int m0 = blockIdx.x * 32;
    float* Sbh = prev + (long)bh * TT * TT;

    const int tid = threadIdx.x;
    const int w = tid >> 6, lane = tid & 63;
    const int fr = lane & 15, kb = lane >> 4;
    const int cr = kb, cc = fr;

    f32x4 acc[2][8] = {};

    // ---- phase 1: S = Q K^T (rows m0..m0+31, all 512 cols) ----
    for (int k0 = 0; k0 < 96; k0 += 32) {
        if (w < 2) {
            int e = w * 512 + lane * 8;
            int r = e >> 5, c = e & 31;
            GLDS(kqv + ((long)((b * TT + m0 + r) * HH + h)) * 288 + 96 + k0 + c,
                 (char*)As + w * 1024);
        }
#pragma unroll
        for (int q = 0; q < 8; ++q) {
            int ci = q * 4 + w;
            int e = ci * 512 + lane * 8;
            int r = e >> 5, c = e & 31;
            GLDS(kqv + ((long)((b * TT + r) * HH + h)) * 288 + k0 + c,
                 (char*)Bs + ci * 1024);
        }
        __syncthreads();
        short8 af[2];
        af[0] = *(const short8*)&As[fr * 32 + kb * 8];
        af[1] = *(const short8*)&As[(16 + fr) * 32 + kb * 8];
#pragma unroll
        for (int fn = 0; fn < 8; ++fn) {
            short8 bf = *(const short8*)&Bs[(w * 128 + fn * 16 + fr) * 32 + kb * 8];
            acc[0][fn] = __builtin_amdgcn_mfma_f32_16x16x32_bf16(af[0], bf, acc[0][fn], 0, 0, 0);
            acc[1][fn] = __builtin_amdgcn_mfma_f32_16x16x32_bf16(af[1], bf, acc[1][fn], 0, 0, 0);
        }
        __syncthreads();
    }

    // ---- phase 2: + prev, write raw, softmax ----
#pragma unroll
    for (int fm = 0; fm < 2; ++fm)
#pragma unroll
        for (int fn = 0; fn < 8; ++fn)
#pragma unroll
            for (int j = 0; j < 4; ++j) {
                int row = m0 + fm * 16 + cr * 4 + j;
                int col = w * 128 + fn * 16 + cc;
                long idx = (long)row * TT + col;
                float pv = scale * acc[fm][fn][j];
                if (addprev) pv += Sbh[idx];
                if (writeprev) Sbh[idx] = pv;
                acc[fm][fn][j] = pv;
            }

#pragma unroll
    for (int fm = 0; fm < 2; ++fm)
#pragma unroll
        for (int j = 0; j < 4; ++j) {
            float mx = -1e30f;
#pragma unroll
            for (int fn = 0; fn < 8; ++fn) mx = fmaxf(mx, acc[fm][fn][j]);
            for (int o = 1; o <= 8; o <<= 1) mx = fmaxf(mx, __shfl_xor(mx, o));
            if (cc == 0) red[w * 32 + fm * 16 + cr * 4 + j] = mx;
        }
    __syncthreads();

    float inv[2][4];
#pragma unroll
    for (int fm = 0; fm < 2; ++fm)
#pragma unroll
        for (int j = 0; j < 4; ++j) {
            int r = fm * 16 + cr * 4 + j;
            float mx = fmaxf(fmaxf(red[r], red[32 + r]), fmaxf(red[64 + r], red[96 + r]));
            float s = 0.f;
#pragma unroll
            for (int fn = 0; fn < 8; ++fn) {
                float e = __expf(acc[fm][fn][j] - mx);
                acc[fm][fn][j] = e;
                s += e;
            }
            for (int o = 1; o <= 8; o <<= 1) s += __shfl_xor(s, o);
            if (cc == 0) red2[w * 32 + r] = s;
        }
    __syncthreads();
#pragma unroll
    for (int fm = 0; fm < 2; ++fm)
#pragma unroll
        for (int j = 0; j < 4; ++j) {
            int r = fm * 16 + cr * 4 + j;
            inv[fm][j] = 1.f / (red2[r] + red2[32 + r] + red2[64 + r] + red2[96 + r]);
        }

    // write P (bf16) into swizzled LDS tile (elem col ^= (row&7)<<3)
#pragma unroll
    for (int fm = 0; fm < 2; ++fm)
#pragma unroll
        for (int fn = 0; fn < 8; ++fn)
#pragma unroll
            for (int j = 0; j < 4; ++j) {
                int row = fm * 16 + cr * 4 + j;
                int col = w * 128 + fn * 16 + cc;
                Pt[row * 512 + (col ^ ((row & 7) << 3))] = f2b(acc[fm][fn][j] * inv[fm][j]);
            }
    __syncthreads();

    // ---- phase 3: attn = P @ V ----
    const int wr = w >> 1, wc2 = w & 1;
    f32x4 po[3] = {};
    for (int j0 = 0; j0 < TT; j0 += 32) {
#pragma unroll
        for (int q = 0; q < 2; ++q) {
            int ci = q * 4 + w;
            if (ci < 6) {
                int e = ci * 512 + lane * 8;
                int r = e >> 5, c = e & 31;
                GLDS(Vt + ((long)(bh * ESS + r)) * TT + j0 + c, (char*)Vs + ci * 1024);
            }
        }
        __syncthreads();
        int prow = wr * 16 + fr;
        short8 pa = *(const short8*)&Pt[prow * 512 + ((j0 + kb * 8) ^ ((prow & 7) << 3))];
#pragma unroll
        for (int fn = 0; fn < 3; ++fn) {
            short8 vb = *(const short8*)&Vs[(wc2 * 48 + fn * 16 + fr) * 32 + kb * 8];
            po[fn] = __builtin_amdgcn_mfma_f32_16x16x32_bf16(pa, vb, po[fn], 0, 0, 0);
        }
        __syncthreads();
    }

#pragma unroll
    for (int fn = 0; fn < 3; ++fn)
#pragma unroll
        for (int j = 0; j < 4; ++j) {
            int grow = m0 + wr * 16 + cr * 4 + j;
            int gcol = h * ESS + wc2 * 48 + fn * 16 + cc;
            attn[((long)(b * TT + grow)) * EMBD + gcol] = f2b(po[fn][j]);
        }
}

// ---------------------------------------------------------------------------
// Extract V from interleaved bf16 kqv, write V^T: Vt[((b,h),s),t]
// ---------------------------------------------------------------------------
__global__ __launch_bounds__(256) void vt_cvt(
    const ushort_t* __restrict__ kqv, ushort_t* __restrict__ Vt)
{
    const int idx = blockIdx.x * 256 + threadIdx.x;
    const int t = idx & 511;
    const int rest = idx >> 9;
    const int s = rest % ESS;
    const int bh = rest / ESS;
    const int h = bh & 7, b = bh >> 3;
    Vt[idx] = kqv[(((long)(b * TT + t) * HH + h) * 288) + 192 + s];
}

// ---------------------------------------------------------------------------
__global__ __launch_bounds__(256) void cvt_f2b(
    const float* __restrict__ in, ushort_t* __restrict__ out)
{
    const int i = blockIdx.x * 256 + threadIdx.x;
    float4 v = ((const float4*)in)[i];
    ushort4v o = {f2b(v.x), f2b(v.y), f2b(v.z), f2b(v.w)};
    ((ushort4v*)out)[i] = o;
}

// ---------------------------------------------------------------------------
__global__ __launch_bounds__(256) void cvt_weights(
    const float* __restrict__ wkqv, const float* __restrict__ wproj,
    const float* __restrict__ w1, const float* __restrict__ w2,
    ushort_t* __restrict__ owkqv, ushort_t* __restrict__ owproj,
    ushort_t* __restrict__ ow1, ushort_t* __restrict__ ow2)
{
    int i4 = blockIdx.x * 256 + threadIdx.x;
    const float* src; ushort_t* dst; int base;
    if (i4 < 6912)        { src = wkqv;  dst = owkqv;  base = 0; }
    else if (i4 < 154368) { src = wproj; dst = owproj; base = 6912; }
    else if (i4 < 744192) { src = w1;    dst = ow1;    base = 154368; }
    else                  { src = w2;    dst = ow2;    base = 744192; }
    int j = i4 - base;
    float4 v = ((const float4*)src)[j];
    ushort4v o = {f2b(v.x), f2b(v.y), f2b(v.z), f2b(v.w)};
    ((ushort4v*)dst)[j] = o;
}

// ---------------------------------------------------------------------------
// x = LayerNorm(x + r0 + r1 (+bias)) * g + b ; also emit bf16 copy.
// ---------------------------------------------------------------------------
__global__ __launch_bounds__(192) void add_ln(
    float* __restrict__ x, const float* __restrict__ r0,
    const float* __restrict__ r1, const float* __restrict__ bias,
    const float* __restrict__ g, const float* __restrict__ bta,
    ushort_t* __restrict__ xb)
{
    const long row = blockIdx.x;
    float4* xr = (float4*)(x + row * EMBD);
    const float4* q0 = (const float4*)(r0 + row * EMBD);
    const float4* q1 = (const float4*)(r1 + row * EMBD);
    __shared__ float sh[4];
    const int tid = threadIdx.x;
    const int lane = tid & 63, w = tid >> 6;

    float4 a = xr[tid], u0 = q0[tid], u1 = q1[tid];
    float v[4] = {a.x + u0.x + u1.x, a.y + u0.y + u1.y,
                  a.z + u0.z + u1.z, a.w + u0.w + u1.w};
    if (bias) {
        float4 b4 = ((const float4*)bias)[tid];
        v[0] += b4.x; v[1] += b4.y; v[2] += b4.z; v[3] += b4.w;
    }
    float s = v[0] + v[1] + v[2] + v[3];
    for (int o = 32; o; o >>= 1) s += __shfl_xor(s, o);
    if (lane == 0) sh[w] = s;
    __syncthreads();
    float mu = (sh[0] + sh[1] + sh[2]) * (1.f / EMBD);

    float var = 0.f;
#pragma unroll
    for (int c = 0; c < 4; ++c) { float d = v[c] - mu; var += d * d; }
    for (int o = 32; o; o >>= 1) var += __shfl_xor(var, o);
    __syncthreads();
    if (lane == 0) sh[w] = var;
    __syncthreads();
    var = (sh[0] + sh[1] + sh[2]) * (1.f / EMBD);
    float rstd = rsqrtf(var + 1e-5f);

    const float4 g4 = ((const float4*)g)[tid];
    const float4 b4 = ((const float4*)bta)[tid];
    float o0 = (v[0] - mu) * rstd * g4.x + b4.x;
    float o1 = (v[1] - mu) * rstd * g4.y + b4.y;
    float o2 = (v[2] - mu) * rstd * g4.z + b4.z;
    float o3 = (v[3] - mu) * rstd * g4.w + b4.w;
    float4 ov = {o0, o1, o2, o3};
    xr[tid] = ov;
    ushort4v ob = {f2b(o0), f2b(o1), f2b(o2), f2b(o3)};
    ((ushort4v*)(xb + row * EMBD))[tid] = ob;
}

// ---------------------------------------------------------------------------
extern "C" void kernel_launch(void* const* d_in, const int* in_sizes, int n_in,
                              void* d_out, int out_size, void* d_ws, size_t ws_size,
                              hipStream_t stream) {
    const float* x_in  = (const float*)d_in[0];
    const float* Wkqv  = (const float*)d_in[1];
    const float* Wproj = (const float*)d_in[2];
    const float* ln1_g = (const float*)d_in[3];
    const float* ln1_b = (const float*)d_in[4];
    const float* ln2_g = (const float*)d_in[5];
    const float* ln2_b = (const float*)d_in[6];
    const float* ff_w1 = (const float*)d_in[7];
    const float* ff_b1 = (const float*)d_in[8];
    const float* ff_w2 = (const float*)d_in[9];
    const float* ff_b2 = (const float*)d_in[10];

    float* x = (float*)d_out;
    char* ws = (char*)d_ws;
    float*    prev   = (float*)(ws);                      // 64 MiB (B*H,T,T) fp32
    ushort_t* kqvb   = (ushort_t*)(ws + 67108864);        // 18 MiB (B,T,H,288) bf16
    ushort_t* Vtb    = (ushort_t*)(ws + 85983232);        // 6 MiB (B*H,96,T) bf16
    float*    res0   = (float*)(ws + 67108864);           // 12 MiB (union kqvb)
    float*    res1   = (float*)(ws + 79691776);           // 12 MiB (union kqvb/Vtb)
    ushort_t* h1b    = (ushort_t*)(ws + 92274688);        // 24 MiB (B,T,4EMB) bf16
    ushort_t* xb     = (ushort_t*)(ws + 125829120);       // 6 MiB bf16
    ushort_t* attnb  = (ushort_t*)(ws + 132120576);       // 6 MiB bf16
    ushort_t* Wkqvb  = (ushort_t*)(ws + 138412032);
    ushort_t* Wprojb = (ushort_t*)(ws + 138467328);
    ushort_t* W1b    = (ushort_t*)(ws + 139646976);
    ushort_t* W2b    = (ushort_t*)(ws + 144365568);       // end ~142.2 MiB

    hipMemcpyAsync(x, x_in, (size_t)BB * TT * EMBD * sizeof(float),
                   hipMemcpyDeviceToDevice, stream);
    cvt_f2b<<<3072, 256, 0, stream>>>(x_in, xb);

    const float scale = 0.10206207261596577f;  // 1/sqrt(96)

    for (int l = 0; l < NLAYER; ++l) {
        const float* wkqv  = Wkqv + (size_t)l * 3 * ESS * ESS;
        const float* wproj = Wproj + (size_t)l * EMBD * EMBD;
        const float* w1 = ff_w1 + (size_t)l * FFD * EMBD;
        const float* b1 = ff_b1 + (size_t)l * FFD;
        const float* w2 = ff_w2 + (size_t)l * EMBD * FFD;
        const float* b2 = ff_b2 + (size_t)l * EMBD;

        cvt_weights<<<5211, 256, 0, stream>>>(wkqv, wproj, w1, w2,
                                              Wkqvb, Wprojb, W1b, W2b);

        // kqv = xh @ wkqv^T
        gemm_mfma<128, 96, 4, 1, 1, 0, 0, 0><<<dim3(3, 256, 1), 256, 0, stream>>>(
            xb, ESS, Wkqvb, ESS, kqvb, 288, ESS, 1.f, nullptr,
            1, 0, 0, 0, 0, 0, 0);

        // Vt bf16
        vt_cvt<<<12288, 256, 0, stream>>>(kqvb, Vtb);

        // fused: prev = scale*QK^T (+prev); attn = softmax @ V
        fused_attn<<<dim3(16, 1, BB * HH), 256, 0, stream>>>(
            kqvb, prev, Vtb, attnb, scale,
            (l == 0) ? 0 : 1, (l == NLAYER - 1) ? 0 : 1);

        // res0/res1 = attn @ Wproj^T split-K
        gemm_mfma<128, 128, 2, 2, 0, 0, 0, 0><<<dim3(6, 32, 2), 256, 0, stream>>>(
            attnb, EMBD, Wprojb, EMBD, res0, EMBD, EMBD / 2, 1.f, nullptr,
            1, 384, 0, 384, 0, (long)(res1 - res0), 0);

        add_ln<<<BB * TT, 192, 0, stream>>>(x, res0, res1, nullptr,
            ln1_g + (size_t)l * EMBD, ln1_b + (size_t)l * EMBD, xb);

        // h1 = gelu(xb @ W1^T + b1)
        gemm_mfma<128, 128, 2, 2, 1, 1, 1, 0><<<dim3(24, 32, 1), 256, 0, stream>>>(
            xb, EMBD, W1b, EMBD, h1b, FFD, EMBD, 1.f, b1,
            1, 0, 0, 0, 0, 0, 0);

        // res0/res1 = h1 @ W2^T split-K (b2 applied in ln2)
        gemm_mfma<128, 128, 2, 2, 0, 0, 0, 0><<<dim3(6, 32, 2), 256, 0, stream>>>(
            h1b, FFD, W2b, FFD, res0, EMBD, FFD / 2, 1.f, nullptr,
            1, 1536, 0, 1536, 0, (long)(res1 - res0), 0);

        add_ln<<<BB * TT, 192, 0, stream>>>(x, res0, res1, b2,
            ln2_g + (size_t)l * EMBD, ln2_b + (size_t)l * EMBD, xb);
    }
}